// Round 2
// baseline (397.237 us; speedup 1.0000x reference)
//
#include <hip/hip_runtime.h>
#include <hip/hip_bf16.h>

// Problem: B=4, S=2048, D=512, H=8, KD=VD=64.
// out[b,s,:] = concat_h( softmax(qk^T*scale_h) @ (v*mask_j) * mask_i ) @ Wo
// Softmax denominator is UNMASKED (mask applied post-softmax, per reference).
// Precision: q,k kept as bf16 hi+lo split; S = hi*hi + hi*lo + lo*hi (3 MFMAs).

typedef __bf16 bf16x8 __attribute__((ext_vector_type(8)));
typedef float  f32x4  __attribute__((ext_vector_type(4)));

#define BB 4
#define SS 2048
#define DD 512
#define HH 8
#define KDIM 64

// ---------------- Kernel A: fused QKV projection (fp32 compute) --------------
// grid 512 blocks x 256 thr. Each block: 16 rows of x. Each thread: 6 outputs
// (one per 256-chunk of the 1536 q|k|v output columns) x 16 rows.
// q,k written as hi+lo bf16 split; v as bf16 hi only.
__global__ __launch_bounds__(256) void qkv_kernel(
    const float* __restrict__ x, const float* __restrict__ Wq,
    const float* __restrict__ Wk, const float* __restrict__ Wv,
    __bf16* __restrict__ qh, __bf16* __restrict__ ql,
    __bf16* __restrict__ kh, __bf16* __restrict__ kl,
    __bf16* __restrict__ v) {
  __shared__ float xs[16 * DD];  // 32KB
  const int t = threadIdx.x;
  const size_t rowbase = (size_t)blockIdx.x * 16;
  for (int i = t; i < 16 * DD; i += 256) xs[i] = x[rowbase * DD + i];
  __syncthreads();

  const float* wp[6];
  __bf16* dsth[6];
  __bf16* dstl[6];
  int hh[6], kk[6];
#pragma unroll
  for (int oo = 0; oo < 6; ++oo) {
    int o = oo * 256 + t;             // 0..1535
    int which = o >> 9;               // 0:q 1:k 2:v
    int rem = o & 511;
    int h = rem >> 6, kd = rem & 63;
    const float* W = (which == 0) ? Wq : (which == 1) ? Wk : Wv;
    wp[oo] = W + (size_t)h * DD * KDIM + kd;
    dsth[oo] = (which == 0) ? qh : (which == 1) ? kh : v;
    dstl[oo] = (which == 0) ? ql : (which == 1) ? kl : (__bf16*)nullptr;
    hh[oo] = h; kk[oo] = kd;
  }

  float acc[6][16];
#pragma unroll
  for (int oo = 0; oo < 6; ++oo)
#pragma unroll
    for (int r = 0; r < 16; ++r) acc[oo][r] = 0.f;

  for (int d4 = 0; d4 < DD / 4; ++d4) {
    float wv[6][4];
#pragma unroll
    for (int oo = 0; oo < 6; ++oo)
#pragma unroll
      for (int u = 0; u < 4; ++u) wv[oo][u] = wp[oo][(size_t)(d4 * 4 + u) * KDIM];
#pragma unroll
    for (int r = 0; r < 16; ++r) {
      float4 xv = *(const float4*)&xs[r * DD + d4 * 4];
#pragma unroll
      for (int oo = 0; oo < 6; ++oo) {
        acc[oo][r] += xv.x * wv[oo][0];
        acc[oo][r] += xv.y * wv[oo][1];
        acc[oo][r] += xv.z * wv[oo][2];
        acc[oo][r] += xv.w * wv[oo][3];
      }
    }
  }

#pragma unroll
  for (int oo = 0; oo < 6; ++oo) {
#pragma unroll
    for (int r = 0; r < 16; ++r) {
      size_t row = rowbase + r;               // b*S + s
      int b = (int)(row >> 11), s = (int)(row & 2047);
      size_t idx = (((size_t)b * HH + hh[oo]) * SS + s) * KDIM + kk[oo];
      float val = acc[oo][r];
      __bf16 hi = (__bf16)val;
      dsth[oo][idx] = hi;
      if (dstl[oo]) dstl[oo][idx] = (__bf16)(val - (float)hi);
    }
  }
}

// ---------------- Kernel B: flash attention (bf16 MFMA, fp32 softmax) --------
// grid (S/64, B*H) x 256 thr (4 waves). Wave w owns q rows [w*16, w*16+16).
// K/V tiles of 64 keys staged in LDS. Online softmax, unmasked denominator.
__global__ __launch_bounds__(256) void attn_kernel(
    const __bf16* __restrict__ qhg, const __bf16* __restrict__ qlg,
    const __bf16* __restrict__ khg, const __bf16* __restrict__ klg,
    const __bf16* __restrict__ vg, const float* __restrict__ mask,
    const float* __restrict__ scales, float* __restrict__ ctx) {
  const int t = threadIdx.x;
  const int l = t & 63, w = t >> 6;
  const int bh = blockIdx.y, b = bh >> 3, h = bh & 7;
  const int q0 = blockIdx.x * 64;

  __shared__ __bf16 ksh[64][72];   // K hi (also used to stage Q hi)
  __shared__ __bf16 ksl[64][72];   // K lo (also used to stage Q lo)
  __shared__ __bf16 vs[64][72];
  __shared__ __bf16 ps[4][16][72]; // per-wave P tile

  const size_t base = (size_t)bh * SS * KDIM;
  const int srow = t >> 2, sc0 = (t & 3) * 16;  // staging: 16 bf16 per thread

  // stage Q tile (hi into ksh, lo into ksl), pull fragments, then reuse LDS
  {
    size_t off = base + (size_t)(q0 + srow) * KDIM + sc0;
    const uint4* sh = (const uint4*)(qhg + off);
    uint4* dh = (uint4*)&ksh[srow][sc0];
    dh[0] = sh[0]; dh[1] = sh[1];
    const uint4* sl = (const uint4*)(qlg + off);
    uint4* dl = (uint4*)&ksl[srow][sc0];
    dl[0] = sl[0]; dl[1] = sl[1];
  }
  __syncthreads();

  bf16x8 aqh[2], aql[2];
  aqh[0] = *(const bf16x8*)&ksh[w * 16 + (l & 15)][(l >> 4) * 8];
  aqh[1] = *(const bf16x8*)&ksh[w * 16 + (l & 15)][32 + (l >> 4) * 8];
  aql[0] = *(const bf16x8*)&ksl[w * 16 + (l & 15)][(l >> 4) * 8];
  aql[1] = *(const bf16x8*)&ksl[w * 16 + (l & 15)][32 + (l >> 4) * 8];

  const float sc_h = scales[h];
  float m[4], lsum[4];
  f32x4 oacc[4];
#pragma unroll
  for (int r = 0; r < 4; ++r) { m[r] = -1e30f; lsum[r] = 0.f; }
#pragma unroll
  for (int nb = 0; nb < 4; ++nb) oacc[nb] = f32x4{0.f, 0.f, 0.f, 0.f};

  for (int kt = 0; kt < SS / 64; ++kt) {
    __syncthreads();  // previous tile fully consumed
    {
      size_t off = base + (size_t)(kt * 64 + srow) * KDIM + sc0;
      const uint4* skh = (const uint4*)(khg + off);
      uint4* dkh = (uint4*)&ksh[srow][sc0];
      dkh[0] = skh[0]; dkh[1] = skh[1];
      const uint4* skl = (const uint4*)(klg + off);
      uint4* dkl = (uint4*)&ksl[srow][sc0];
      dkl[0] = skl[0]; dkl[1] = skl[1];
      const uint4* sv = (const uint4*)(vg + off);
      uint4* dv = (uint4*)&vs[srow][sc0];
      dv[0] = sv[0]; dv[1] = sv[1];
    }
    __syncthreads();

    // S = Q K^T with hi/lo split: hi*hi + hi*lo + lo*hi
    f32x4 s[4];
#pragma unroll
    for (int jb = 0; jb < 4; ++jb) {
      s[jb] = f32x4{0.f, 0.f, 0.f, 0.f};
#pragma unroll
      for (int kb = 0; kb < 2; ++kb) {
        bf16x8 bkh = *(const bf16x8*)&ksh[jb * 16 + (l & 15)][kb * 32 + (l >> 4) * 8];
        bf16x8 bkl = *(const bf16x8*)&ksl[jb * 16 + (l & 15)][kb * 32 + (l >> 4) * 8];
        s[jb] = __builtin_amdgcn_mfma_f32_16x16x32_bf16(aqh[kb], bkh, s[jb], 0, 0, 0);
        s[jb] = __builtin_amdgcn_mfma_f32_16x16x32_bf16(aqh[kb], bkl, s[jb], 0, 0, 0);
        s[jb] = __builtin_amdgcn_mfma_f32_16x16x32_bf16(aql[kb], bkh, s[jb], 0, 0, 0);
      }
    }
#pragma unroll
    for (int jb = 0; jb < 4; ++jb) s[jb] *= sc_h;

    float mask_j[4];
#pragma unroll
    for (int jb = 0; jb < 4; ++jb)
      mask_j[jb] = mask[b * SS + kt * 64 + jb * 16 + (l & 15)];

    // online softmax per owned row (rows (l>>4)*4 + r)
#pragma unroll
    for (int r = 0; r < 4; ++r) {
      float mt = fmaxf(fmaxf(s[0][r], s[1][r]), fmaxf(s[2][r], s[3][r]));
#pragma unroll
      for (int i = 1; i < 16; i <<= 1) mt = fmaxf(mt, __shfl_xor(mt, i, 64));
      float mn = fmaxf(m[r], mt);
      float resc = __expf(m[r] - mn);
      float pr[4], psumv = 0.f;
#pragma unroll
      for (int jb = 0; jb < 4; ++jb) { pr[jb] = __expf(s[jb][r] - mn); psumv += pr[jb]; }
#pragma unroll
      for (int i = 1; i < 16; i <<= 1) psumv += __shfl_xor(psumv, i, 64);
      lsum[r] = lsum[r] * resc + psumv;
      m[r] = mn;
#pragma unroll
      for (int nb = 0; nb < 4; ++nb) oacc[nb][r] *= resc;
#pragma unroll
      for (int jb = 0; jb < 4; ++jb)
        ps[w][(l >> 4) * 4 + r][jb * 16 + (l & 15)] = (__bf16)(pr[jb] * mask_j[jb]);
    }

    // O += P V
#pragma unroll
    for (int kb = 0; kb < 2; ++kb) {
      bf16x8 pa = *(const bf16x8*)&ps[w][l & 15][kb * 32 + (l >> 4) * 8];
#pragma unroll
      for (int nb = 0; nb < 4; ++nb) {
        bf16x8 bv;
#pragma unroll
        for (int jj = 0; jj < 8; ++jj)
          bv[jj] = vs[kb * 32 + (l >> 4) * 8 + jj][nb * 16 + (l & 15)];
        oacc[nb] = __builtin_amdgcn_mfma_f32_16x16x32_bf16(pa, bv, oacc[nb], 0, 0, 0);
      }
    }
  }

  // epilogue: ctx[b, s, h*64+vd] = mask_i * O / lsum
#pragma unroll
  for (int r = 0; r < 4; ++r) {
    int row = q0 + w * 16 + (l >> 4) * 4 + r;
    float mi = mask[b * SS + row];
    float inv = mi / lsum[r];
#pragma unroll
    for (int nb = 0; nb < 4; ++nb) {
      int vd = nb * 16 + (l & 15);
      ctx[((size_t)(b * SS + row)) * (HH * KDIM) + h * KDIM + vd] = oacc[nb][r] * inv;
    }
  }
}

// ---------------- Kernel C: output projection (fp32) -------------------------
// ctx [8192, 512] @ Wo [512, 64] -> out [8192, 64]. 512 blocks x 256 thr,
// 16 rows per block; thread: col = t&63, 4 rows.
__global__ __launch_bounds__(256) void oproj_kernel(
    const float* __restrict__ ctx, const float* __restrict__ Wo,
    float* __restrict__ out) {
  __shared__ float xs[16 * 512];  // 32KB
  const int t = threadIdx.x;
  const size_t rowbase = (size_t)blockIdx.x * 16;
  for (int i = t; i < 16 * 512; i += 256) xs[i] = ctx[rowbase * 512 + i];
  __syncthreads();

  const int col = t & 63, rg = t >> 6;
  float acc[4] = {0.f, 0.f, 0.f, 0.f};
  for (int d4 = 0; d4 < 128; ++d4) {
    float wv[4];
#pragma unroll
    for (int u = 0; u < 4; ++u) wv[u] = Wo[(size_t)(d4 * 4 + u) * 64 + col];
#pragma unroll
    for (int rr = 0; rr < 4; ++rr) {
      float4 xv = *(const float4*)&xs[(rg * 4 + rr) * 512 + d4 * 4];
      acc[rr] += xv.x * wv[0];
      acc[rr] += xv.y * wv[1];
      acc[rr] += xv.z * wv[2];
      acc[rr] += xv.w * wv[3];
    }
  }
#pragma unroll
  for (int rr = 0; rr < 4; ++rr)
    out[(rowbase + rg * 4 + rr) * 64 + col] = acc[rr];
}

// ---------------- launch -----------------------------------------------------
extern "C" void kernel_launch(void* const* d_in, const int* in_sizes, int n_in,
                              void* d_out, int out_size, void* d_ws, size_t ws_size,
                              hipStream_t stream) {
  const float* x     = (const float*)d_in[0];
  const float* mask  = (const float*)d_in[1];
  const float* Wq    = (const float*)d_in[2];
  const float* Wk    = (const float*)d_in[3];
  const float* Wv    = (const float*)d_in[4];
  const float* Wo    = (const float*)d_in[5];
  const float* scales= (const float*)d_in[6];
  float* out = (float*)d_out;

  char* ws = (char*)d_ws;
  const size_t qkv_bytes = (size_t)BB * HH * SS * KDIM * sizeof(__bf16);  // 8MB each
  __bf16* qhb = (__bf16*)(ws);
  __bf16* qlb = (__bf16*)(ws + qkv_bytes);
  __bf16* khb = (__bf16*)(ws + 2 * qkv_bytes);
  __bf16* klb = (__bf16*)(ws + 3 * qkv_bytes);
  __bf16* vb  = (__bf16*)(ws + 4 * qkv_bytes);
  float*  ctx = (float*)(ws + 5 * qkv_bytes);  // 16MB

  qkv_kernel<<<512, 256, 0, stream>>>(x, Wq, Wk, Wv, qhb, qlb, khb, klb, vb);
  attn_kernel<<<dim3(SS / 64, BB * HH), 256, 0, stream>>>(qhb, qlb, khb, klb, vb, mask, scales, ctx);
  oproj_kernel<<<512, 256, 0, stream>>>(ctx, Wo, out);
}

// Round 3
// 278.166 us; speedup vs baseline: 1.4281x; 1.4281x over previous
//
#include <hip/hip_runtime.h>
#include <hip/hip_bf16.h>

// Problem: B=4, S=2048, D=512, H=8, KD=VD=64.
// out[b,s,:] = concat_h( softmax(qk^T*scale_h) @ (v*mask_j) * mask_i ) @ Wo
// Softmax denominator is UNMASKED (mask applied post-softmax, per reference).
// Precision: all GEMM inputs kept as bf16 hi+lo split; products use 3 MFMAs
// (hi*hi + hi*lo + lo*hi), dropping lo*lo (~2^-18 relative).

typedef __bf16 bf16x8 __attribute__((ext_vector_type(8)));
typedef float  f32x4  __attribute__((ext_vector_type(4)));

#define BB 4
#define SS 2048
#define DD 512
#define HH 8
#define KDIM 64

#define GLOAD_LDS16(gp, lp)                                                   \
  __builtin_amdgcn_global_load_lds(                                          \
      (const __attribute__((address_space(1))) void*)(gp),                    \
      (__attribute__((address_space(3))) void*)(lp), 16, 0, 0)

// ---------------- convert_x: x fp32 -> xh, xl bf16 [8192,512] ----------------
__global__ __launch_bounds__(256) void convert_x(
    const float* __restrict__ x, __bf16* __restrict__ xh, __bf16* __restrict__ xl) {
  size_t i = ((size_t)blockIdx.x * 256 + threadIdx.x) * 8;
  float4 a = *(const float4*)&x[i];
  float4 b = *(const float4*)&x[i + 4];
  float vv[8] = {a.x, a.y, a.z, a.w, b.x, b.y, b.z, b.w};
  __bf16 hb[8], lb[8];
#pragma unroll
  for (int u = 0; u < 8; ++u) {
    hb[u] = (__bf16)vv[u];
    lb[u] = (__bf16)(vv[u] - (float)hb[u]);
  }
  *(uint4*)&xh[i] = *(uint4*)hb;
  *(uint4*)&xl[i] = *(uint4*)lb;
}

// ---------------- convert_w: Wq/Wk/Wv [8,512,64] -> wt hi/lo [1536][512] -----
// wt[n][k] = Wsel[h*512*64 + k*64 + kd], n = which*512 + h*64 + kd.
// grid (8 kblocks, 24 hw). LDS transpose of a 64x64 tile.
__global__ __launch_bounds__(256) void convert_w(
    const float* __restrict__ Wq, const float* __restrict__ Wk,
    const float* __restrict__ Wv, __bf16* __restrict__ wth,
    __bf16* __restrict__ wtl) {
  __shared__ float s_tile[64][65];
  const int t = threadIdx.x;
  const int kb = blockIdx.x;          // 0..7
  const int hw = blockIdx.y;          // 0..23
  const int which = hw >> 3, h = hw & 7;
  const float* W = (which == 0) ? Wq : (which == 1) ? Wk : Wv;
  const float* src = W + (size_t)h * DD * KDIM + (size_t)kb * 64 * KDIM;

  {
    int kk = t >> 2, c0 = (t & 3) * 16;
#pragma unroll
    for (int u = 0; u < 4; ++u)
      *(float4*)&s_tile[kk][c0 + u * 4] = *(const float4*)&src[kk * KDIM + c0 + u * 4];
  }
  __syncthreads();

  int kd = t >> 2, kk0 = (t & 3) * 16;
  int n = which * 512 + h * 64 + kd;
  __bf16 hb[16], lb[16];
#pragma unroll
  for (int u = 0; u < 16; ++u) {
    float val = s_tile[kk0 + u][kd];
    hb[u] = (__bf16)val;
    lb[u] = (__bf16)(val - (float)hb[u]);
  }
  size_t off = (size_t)n * DD + kb * 64 + kk0;
  *(uint4*)&wth[off] = *(uint4*)&hb[0];
  *(uint4*)&wth[off + 8] = *(uint4*)&hb[8];
  *(uint4*)&wtl[off] = *(uint4*)&lb[0];
  *(uint4*)&wtl[off + 8] = *(uint4*)&lb[8];
}

// ---------------- qkv_gemm: [8192,512] @ [512,1536] via bf16 hi/lo MFMA ------
// 128x128 tile, BK=32, 4 waves (2x2 of 64x64), global_load_lds staging.
// Epilogue re-splits q,k into hi/lo bf16, v into bf16, layout [B*H, S, 64].
__global__ __launch_bounds__(256) void qkv_gemm(
    const __bf16* __restrict__ xh, const __bf16* __restrict__ xl,
    const __bf16* __restrict__ wth, const __bf16* __restrict__ wtl,
    __bf16* __restrict__ qh, __bf16* __restrict__ ql,
    __bf16* __restrict__ kh, __bf16* __restrict__ kl,
    __bf16* __restrict__ v) {
  __shared__ __bf16 Ah[128 * 32], Al[128 * 32], Bh[128 * 32], Bl[128 * 32];
  const int t = threadIdx.x, l = t & 63, w = t >> 6;
  const int wr = w >> 1, wc = w & 1;
  const int m0 = blockIdx.y * 128, n0 = blockIdx.x * 128;

  f32x4 acc[4][4];
#pragma unroll
  for (int m = 0; m < 4; ++m)
#pragma unroll
    for (int n = 0; n < 4; ++n) acc[m][n] = f32x4{0.f, 0.f, 0.f, 0.f};

  const int rl = l >> 2, ce = (l & 3) * 8;  // staging: 16 rows x 32 el per instr

  for (int kt = 0; kt < 16; ++kt) {
    const int k0 = kt * 32;
    __syncthreads();
#pragma unroll
    for (int i = 0; i < 2; ++i) {
      const int row = w * 32 + i * 16;  // wave-uniform group base
      const size_t aoff = (size_t)(m0 + row + rl) * DD + k0 + ce;
      const size_t boff = (size_t)(n0 + row + rl) * DD + k0 + ce;
      GLOAD_LDS16(xh + aoff, &Ah[row * 32]);
      GLOAD_LDS16(xl + aoff, &Al[row * 32]);
      GLOAD_LDS16(wth + boff, &Bh[row * 32]);
      GLOAD_LDS16(wtl + boff, &Bl[row * 32]);
    }
    __syncthreads();

    bf16x8 ah[4], al[4], bh[4], bl[4];
#pragma unroll
    for (int m = 0; m < 4; ++m) {
      int r = wr * 64 + m * 16 + (l & 15);
      ah[m] = *(const bf16x8*)&Ah[r * 32 + (l >> 4) * 8];
      al[m] = *(const bf16x8*)&Al[r * 32 + (l >> 4) * 8];
    }
#pragma unroll
    for (int n = 0; n < 4; ++n) {
      int r = wc * 64 + n * 16 + (l & 15);
      bh[n] = *(const bf16x8*)&Bh[r * 32 + (l >> 4) * 8];
      bl[n] = *(const bf16x8*)&Bl[r * 32 + (l >> 4) * 8];
    }
#pragma unroll
    for (int m = 0; m < 4; ++m)
#pragma unroll
      for (int n = 0; n < 4; ++n) {
        acc[m][n] = __builtin_amdgcn_mfma_f32_16x16x32_bf16(ah[m], bh[n], acc[m][n], 0, 0, 0);
        acc[m][n] = __builtin_amdgcn_mfma_f32_16x16x32_bf16(ah[m], bl[n], acc[m][n], 0, 0, 0);
        acc[m][n] = __builtin_amdgcn_mfma_f32_16x16x32_bf16(al[m], bh[n], acc[m][n], 0, 0, 0);
      }
  }

  // epilogue: scatter to qh/ql, kh/kl, v in [B*H, S, 64] layout
#pragma unroll
  for (int n = 0; n < 4; ++n) {
    int colg = n0 + wc * 64 + n * 16 + (l & 15);
    int which = colg >> 9, rem = colg & 511;
    int h = rem >> 6, kd = rem & 63;
    __bf16* dh = (which == 0) ? qh : (which == 1) ? kh : v;
    __bf16* dl = (which == 0) ? ql : (which == 1) ? kl : (__bf16*)nullptr;
#pragma unroll
    for (int m = 0; m < 4; ++m) {
#pragma unroll
      for (int j = 0; j < 4; ++j) {
        int row = m0 + wr * 64 + m * 16 + (l >> 4) * 4 + j;
        int b = row >> 11, s = row & 2047;
        size_t idx = (((size_t)b * HH + h) * SS + s) * KDIM + kd;
        float val = acc[m][n][j];
        __bf16 hi = (__bf16)val;
        dh[idx] = hi;
        if (dl) dl[idx] = (__bf16)(val - (float)hi);
      }
    }
  }
}

// ---------------- Kernel B: flash attention (bf16 MFMA, fp32 softmax) --------
__global__ __launch_bounds__(256) void attn_kernel(
    const __bf16* __restrict__ qhg, const __bf16* __restrict__ qlg,
    const __bf16* __restrict__ khg, const __bf16* __restrict__ klg,
    const __bf16* __restrict__ vg, const float* __restrict__ mask,
    const float* __restrict__ scales, float* __restrict__ ctx) {
  const int t = threadIdx.x;
  const int l = t & 63, w = t >> 6;
  const int bh = blockIdx.y, b = bh >> 3, h = bh & 7;
  const int q0 = blockIdx.x * 64;

  __shared__ __bf16 ksh[64][72];
  __shared__ __bf16 ksl[64][72];
  __shared__ __bf16 vs[64][72];
  __shared__ __bf16 ps[4][16][72];

  const size_t base = (size_t)bh * SS * KDIM;
  const int srow = t >> 2, sc0 = (t & 3) * 16;

  {
    size_t off = base + (size_t)(q0 + srow) * KDIM + sc0;
    const uint4* sh = (const uint4*)(qhg + off);
    uint4* dh = (uint4*)&ksh[srow][sc0];
    dh[0] = sh[0]; dh[1] = sh[1];
    const uint4* sl = (const uint4*)(qlg + off);
    uint4* dl = (uint4*)&ksl[srow][sc0];
    dl[0] = sl[0]; dl[1] = sl[1];
  }
  __syncthreads();

  bf16x8 aqh[2], aql[2];
  aqh[0] = *(const bf16x8*)&ksh[w * 16 + (l & 15)][(l >> 4) * 8];
  aqh[1] = *(const bf16x8*)&ksh[w * 16 + (l & 15)][32 + (l >> 4) * 8];
  aql[0] = *(const bf16x8*)&ksl[w * 16 + (l & 15)][(l >> 4) * 8];
  aql[1] = *(const bf16x8*)&ksl[w * 16 + (l & 15)][32 + (l >> 4) * 8];

  const float sc_h = scales[h];
  float m[4], lsum[4];
  f32x4 oacc[4];
#pragma unroll
  for (int r = 0; r < 4; ++r) { m[r] = -1e30f; lsum[r] = 0.f; }
#pragma unroll
  for (int nb = 0; nb < 4; ++nb) oacc[nb] = f32x4{0.f, 0.f, 0.f, 0.f};

  for (int kt = 0; kt < SS / 64; ++kt) {
    __syncthreads();
    {
      size_t off = base + (size_t)(kt * 64 + srow) * KDIM + sc0;
      const uint4* skh = (const uint4*)(khg + off);
      uint4* dkh = (uint4*)&ksh[srow][sc0];
      dkh[0] = skh[0]; dkh[1] = skh[1];
      const uint4* skl = (const uint4*)(klg + off);
      uint4* dkl = (uint4*)&ksl[srow][sc0];
      dkl[0] = skl[0]; dkl[1] = skl[1];
      const uint4* sv = (const uint4*)(vg + off);
      uint4* dv = (uint4*)&vs[srow][sc0];
      dv[0] = sv[0]; dv[1] = sv[1];
    }
    __syncthreads();

    f32x4 s[4];
#pragma unroll
    for (int jb = 0; jb < 4; ++jb) {
      s[jb] = f32x4{0.f, 0.f, 0.f, 0.f};
#pragma unroll
      for (int kb = 0; kb < 2; ++kb) {
        bf16x8 bkh = *(const bf16x8*)&ksh[jb * 16 + (l & 15)][kb * 32 + (l >> 4) * 8];
        bf16x8 bkl = *(const bf16x8*)&ksl[jb * 16 + (l & 15)][kb * 32 + (l >> 4) * 8];
        s[jb] = __builtin_amdgcn_mfma_f32_16x16x32_bf16(aqh[kb], bkh, s[jb], 0, 0, 0);
        s[jb] = __builtin_amdgcn_mfma_f32_16x16x32_bf16(aqh[kb], bkl, s[jb], 0, 0, 0);
        s[jb] = __builtin_amdgcn_mfma_f32_16x16x32_bf16(aql[kb], bkh, s[jb], 0, 0, 0);
      }
    }
#pragma unroll
    for (int jb = 0; jb < 4; ++jb) s[jb] *= sc_h;

    float mask_j[4];
#pragma unroll
    for (int jb = 0; jb < 4; ++jb)
      mask_j[jb] = mask[b * SS + kt * 64 + jb * 16 + (l & 15)];

#pragma unroll
    for (int r = 0; r < 4; ++r) {
      float mt = fmaxf(fmaxf(s[0][r], s[1][r]), fmaxf(s[2][r], s[3][r]));
#pragma unroll
      for (int i = 1; i < 16; i <<= 1) mt = fmaxf(mt, __shfl_xor(mt, i, 64));
      float mn = fmaxf(m[r], mt);
      float resc = __expf(m[r] - mn);
      float pr[4], psumv = 0.f;
#pragma unroll
      for (int jb = 0; jb < 4; ++jb) { pr[jb] = __expf(s[jb][r] - mn); psumv += pr[jb]; }
#pragma unroll
      for (int i = 1; i < 16; i <<= 1) psumv += __shfl_xor(psumv, i, 64);
      lsum[r] = lsum[r] * resc + psumv;
      m[r] = mn;
#pragma unroll
      for (int nb = 0; nb < 4; ++nb) oacc[nb][r] *= resc;
#pragma unroll
      for (int jb = 0; jb < 4; ++jb)
        ps[w][(l >> 4) * 4 + r][jb * 16 + (l & 15)] = (__bf16)(pr[jb] * mask_j[jb]);
    }

#pragma unroll
    for (int kb = 0; kb < 2; ++kb) {
      bf16x8 pa = *(const bf16x8*)&ps[w][l & 15][kb * 32 + (l >> 4) * 8];
#pragma unroll
      for (int nb = 0; nb < 4; ++nb) {
        bf16x8 bv;
#pragma unroll
        for (int jj = 0; jj < 8; ++jj)
          bv[jj] = vs[kb * 32 + (l >> 4) * 8 + jj][nb * 16 + (l & 15)];
        oacc[nb] = __builtin_amdgcn_mfma_f32_16x16x32_bf16(pa, bv, oacc[nb], 0, 0, 0);
      }
    }
  }

#pragma unroll
  for (int r = 0; r < 4; ++r) {
    int row = q0 + w * 16 + (l >> 4) * 4 + r;
    float mi = mask[b * SS + row];
    float inv = mi / lsum[r];
#pragma unroll
    for (int nb = 0; nb < 4; ++nb) {
      int vd = nb * 16 + (l & 15);
      ctx[((size_t)(b * SS + row)) * (HH * KDIM) + h * KDIM + vd] = oacc[nb][r] * inv;
    }
  }
}

// ---------------- Kernel C: output projection (fp32) -------------------------
__global__ __launch_bounds__(256) void oproj_kernel(
    const float* __restrict__ ctx, const float* __restrict__ Wo,
    float* __restrict__ out) {
  __shared__ float xs[16 * 512];
  const int t = threadIdx.x;
  const size_t rowbase = (size_t)blockIdx.x * 16;
  for (int i = t; i < 16 * 512; i += 256) xs[i] = ctx[rowbase * 512 + i];
  __syncthreads();

  const int col = t & 63, rg = t >> 6;
  float acc[4] = {0.f, 0.f, 0.f, 0.f};
  for (int d4 = 0; d4 < 128; ++d4) {
    float wv[4];
#pragma unroll
    for (int u = 0; u < 4; ++u) wv[u] = Wo[(size_t)(d4 * 4 + u) * 64 + col];
#pragma unroll
    for (int rr = 0; rr < 4; ++rr) {
      float4 xv = *(const float4*)&xs[(rg * 4 + rr) * 512 + d4 * 4];
      acc[rr] += xv.x * wv[0];
      acc[rr] += xv.y * wv[1];
      acc[rr] += xv.z * wv[2];
      acc[rr] += xv.w * wv[3];
    }
  }
#pragma unroll
  for (int rr = 0; rr < 4; ++rr)
    out[(rowbase + rg * 4 + rr) * 64 + col] = acc[rr];
}

// ---------------- launch -----------------------------------------------------
extern "C" void kernel_launch(void* const* d_in, const int* in_sizes, int n_in,
                              void* d_out, int out_size, void* d_ws, size_t ws_size,
                              hipStream_t stream) {
  const float* x     = (const float*)d_in[0];
  const float* mask  = (const float*)d_in[1];
  const float* Wq    = (const float*)d_in[2];
  const float* Wk    = (const float*)d_in[3];
  const float* Wv    = (const float*)d_in[4];
  const float* Wo    = (const float*)d_in[5];
  const float* scales= (const float*)d_in[6];
  float* out = (float*)d_out;

  char* ws = (char*)d_ws;
  const size_t MB = 1024 * 1024;
  const size_t xb = (size_t)BB * SS * DD * sizeof(__bf16);         // 8MB
  const size_t wb = (size_t)3 * 512 * DD * sizeof(__bf16);         // 1.5MB
  const size_t qb = (size_t)BB * HH * SS * KDIM * sizeof(__bf16);  // 8MB

  __bf16* xhb = (__bf16*)(ws);
  __bf16* xlb = (__bf16*)(ws + xb);
  __bf16* wthb = (__bf16*)(ws + 2 * xb);
  __bf16* wtlb = (__bf16*)(ws + 2 * xb + wb);
  char* p = ws + 2 * xb + 2 * wb;
  __bf16* qhb = (__bf16*)(p);
  __bf16* qlb = (__bf16*)(p + qb);
  __bf16* khb = (__bf16*)(p + 2 * qb);
  __bf16* klb = (__bf16*)(p + 3 * qb);
  __bf16* vb  = (__bf16*)(p + 4 * qb);
  float*  ctx = (float*)(p + 5 * qb);
  (void)MB; (void)ws_size;

  convert_x<<<2048, 256, 0, stream>>>(x, xhb, xlb);
  convert_w<<<dim3(8, 24), 256, 0, stream>>>(Wq, Wk, Wv, wthb, wtlb);
  qkv_gemm<<<dim3(12, 64), 256, 0, stream>>>(xhb, xlb, wthb, wtlb,
                                             qhb, qlb, khb, klb, vb);
  attn_kernel<<<dim3(SS / 64, BB * HH), 256, 0, stream>>>(qhb, qlb, khb, klb, vb, mask, scales, ctx);
  oproj_kernel<<<512, 256, 0, stream>>>(ctx, Wo, out);
}

// Round 4
// 216.425 us; speedup vs baseline: 1.8354x; 1.2853x over previous
//
#include <hip/hip_runtime.h>
#include <hip/hip_bf16.h>

// Problem: B=4, S=2048, D=512, H=8, KD=VD=64.
// out[b,s,:] = concat_h( softmax(qk^T*scale_h) @ (v*mask_j) * mask_i ) @ Wo
// Softmax denominator is UNMASKED (mask applied post-softmax, per reference).
// Precision: GEMM inputs bf16 hi+lo split; products = hi*hi + hi*lo + lo*hi.
// Attention v2: swapped QK^T (S^T in regs), P via LDS b64/b128, V^T premasked.

typedef __bf16 bf16x8 __attribute__((ext_vector_type(8)));
typedef float  f32x4  __attribute__((ext_vector_type(4)));

#define BB 4
#define SS 2048
#define DD 512
#define HH 8
#define KDIM 64

#define GLOAD_LDS16(gp, lp)                                                   \
  __builtin_amdgcn_global_load_lds(                                          \
      (const __attribute__((address_space(1))) void*)(gp),                    \
      (__attribute__((address_space(3))) void*)(lp), 16, 0, 0)

// ---------------- convert_x: x fp32 -> xh, xl bf16 [8192,512] ----------------
__global__ __launch_bounds__(256) void convert_x(
    const float* __restrict__ x, __bf16* __restrict__ xh, __bf16* __restrict__ xl) {
  size_t i = ((size_t)blockIdx.x * 256 + threadIdx.x) * 8;
  float4 a = *(const float4*)&x[i];
  float4 b = *(const float4*)&x[i + 4];
  float vv[8] = {a.x, a.y, a.z, a.w, b.x, b.y, b.z, b.w};
  __bf16 hb[8], lb[8];
#pragma unroll
  for (int u = 0; u < 8; ++u) {
    hb[u] = (__bf16)vv[u];
    lb[u] = (__bf16)(vv[u] - (float)hb[u]);
  }
  *(uint4*)&xh[i] = *(uint4*)hb;
  *(uint4*)&xl[i] = *(uint4*)lb;
}

// ---------------- convert_w: Wq/Wk/Wv [8,512,64] -> wt hi/lo [1536][512] -----
__global__ __launch_bounds__(256) void convert_w(
    const float* __restrict__ Wq, const float* __restrict__ Wk,
    const float* __restrict__ Wv, __bf16* __restrict__ wth,
    __bf16* __restrict__ wtl) {
  __shared__ float s_tile[64][65];
  const int t = threadIdx.x;
  const int kb = blockIdx.x;          // 0..7
  const int hw = blockIdx.y;          // 0..23
  const int which = hw >> 3, h = hw & 7;
  const float* W = (which == 0) ? Wq : (which == 1) ? Wk : Wv;
  const float* src = W + (size_t)h * DD * KDIM + (size_t)kb * 64 * KDIM;

  {
    int kk = t >> 2, c0 = (t & 3) * 16;
#pragma unroll
    for (int u = 0; u < 4; ++u)
      *(float4*)&s_tile[kk][c0 + u * 4] = *(const float4*)&src[kk * KDIM + c0 + u * 4];
  }
  __syncthreads();

  int kd = t >> 2, kk0 = (t & 3) * 16;
  int n = which * 512 + h * 64 + kd;
  __bf16 hb[16], lb[16];
#pragma unroll
  for (int u = 0; u < 16; ++u) {
    float val = s_tile[kk0 + u][kd];
    hb[u] = (__bf16)val;
    lb[u] = (__bf16)(val - (float)hb[u]);
  }
  size_t off = (size_t)n * DD + kb * 64 + kk0;
  *(uint4*)&wth[off] = *(uint4*)&hb[0];
  *(uint4*)&wth[off + 8] = *(uint4*)&hb[8];
  *(uint4*)&wtl[off] = *(uint4*)&lb[0];
  *(uint4*)&wtl[off + 8] = *(uint4*)&lb[8];
}

// ---------------- qkv_gemm: [8192,512] @ [512,1536] via bf16 hi/lo MFMA ------
// Epilogue: q,k -> hi/lo bf16 [B*H,S,64]; v -> premasked V^T [B*H,64,S].
__global__ __launch_bounds__(256) void qkv_gemm(
    const __bf16* __restrict__ xh, const __bf16* __restrict__ xl,
    const __bf16* __restrict__ wth, const __bf16* __restrict__ wtl,
    const float* __restrict__ mask,
    __bf16* __restrict__ qh, __bf16* __restrict__ ql,
    __bf16* __restrict__ kh, __bf16* __restrict__ kl,
    __bf16* __restrict__ vT) {
  __shared__ __bf16 Ah[128 * 32], Al[128 * 32], Bh[128 * 32], Bl[128 * 32];
  const int t = threadIdx.x, l = t & 63, w = t >> 6;
  const int wr = w >> 1, wc = w & 1;
  const int m0 = blockIdx.y * 128, n0 = blockIdx.x * 128;

  f32x4 acc[4][4];
#pragma unroll
  for (int m = 0; m < 4; ++m)
#pragma unroll
    for (int n = 0; n < 4; ++n) acc[m][n] = f32x4{0.f, 0.f, 0.f, 0.f};

  const int rl = l >> 2, ce = (l & 3) * 8;

  for (int kt = 0; kt < 16; ++kt) {
    const int k0 = kt * 32;
    __syncthreads();
#pragma unroll
    for (int i = 0; i < 2; ++i) {
      const int row = w * 32 + i * 16;
      const size_t aoff = (size_t)(m0 + row + rl) * DD + k0 + ce;
      const size_t boff = (size_t)(n0 + row + rl) * DD + k0 + ce;
      GLOAD_LDS16(xh + aoff, &Ah[row * 32]);
      GLOAD_LDS16(xl + aoff, &Al[row * 32]);
      GLOAD_LDS16(wth + boff, &Bh[row * 32]);
      GLOAD_LDS16(wtl + boff, &Bl[row * 32]);
    }
    __syncthreads();

    bf16x8 ah[4], al[4], bh[4], bl[4];
#pragma unroll
    for (int m = 0; m < 4; ++m) {
      int r = wr * 64 + m * 16 + (l & 15);
      ah[m] = *(const bf16x8*)&Ah[r * 32 + (l >> 4) * 8];
      al[m] = *(const bf16x8*)&Al[r * 32 + (l >> 4) * 8];
    }
#pragma unroll
    for (int n = 0; n < 4; ++n) {
      int r = wc * 64 + n * 16 + (l & 15);
      bh[n] = *(const bf16x8*)&Bh[r * 32 + (l >> 4) * 8];
      bl[n] = *(const bf16x8*)&Bl[r * 32 + (l >> 4) * 8];
    }
#pragma unroll
    for (int m = 0; m < 4; ++m)
#pragma unroll
      for (int n = 0; n < 4; ++n) {
        acc[m][n] = __builtin_amdgcn_mfma_f32_16x16x32_bf16(ah[m], bh[n], acc[m][n], 0, 0, 0);
        acc[m][n] = __builtin_amdgcn_mfma_f32_16x16x32_bf16(ah[m], bl[n], acc[m][n], 0, 0, 0);
        acc[m][n] = __builtin_amdgcn_mfma_f32_16x16x32_bf16(al[m], bh[n], acc[m][n], 0, 0, 0);
      }
  }

#pragma unroll
  for (int n = 0; n < 4; ++n) {
    int colg = n0 + wc * 64 + n * 16 + (l & 15);
    int which = colg >> 9, rem = colg & 511;
    int h = rem >> 6, kd = rem & 63;
#pragma unroll
    for (int m = 0; m < 4; ++m) {
      int row0 = m0 + wr * 64 + m * 16 + (l >> 4) * 4;  // 4 consecutive rows
      if (which == 2) {
        // premasked V^T: vT[(bh*64+kd)*SS + s], s contiguous over j
        int b = row0 >> 11, s0 = row0 & 2047;
        __bf16 tmp[4] __attribute__((aligned(8)));
#pragma unroll
        for (int j = 0; j < 4; ++j)
          tmp[j] = (__bf16)(acc[m][n][j] * mask[row0 + j]);
        *(uint2*)&vT[((size_t)(b * HH + h) * KDIM + kd) * SS + s0] = *(uint2*)tmp;
      } else {
        __bf16* dh = (which == 0) ? qh : kh;
        __bf16* dl = (which == 0) ? ql : kl;
#pragma unroll
        for (int j = 0; j < 4; ++j) {
          int row = row0 + j;
          int b = row >> 11, s = row & 2047;
          size_t idx = (((size_t)b * HH + h) * SS + s) * KDIM + kd;
          float val = acc[m][n][j];
          __bf16 hi = (__bf16)val;
          dh[idx] = hi;
          dl[idx] = (__bf16)(val - (float)hi);
        }
      }
    }
  }
}

// ---------------- Kernel B: flash attention v2 -------------------------------
// grid (S/128, B*H) x 256 thr (4 waves). Wave w owns q rows [w*32, w*32+32).
// Swapped QK^T: St = mfma(K_frag, Q_frag) -> lane holds 16 scores of ONE q-row.
__global__ __launch_bounds__(256) void attn_kernel(
    const __bf16* __restrict__ qhg, const __bf16* __restrict__ qlg,
    const __bf16* __restrict__ khg, const __bf16* __restrict__ klg,
    const __bf16* __restrict__ vTg, const float* __restrict__ mask,
    const float* __restrict__ scales, float* __restrict__ ctx) {
  const int t = threadIdx.x;
  const int l = t & 63, w = t >> 6;
  const int bh = blockIdx.y, b = bh >> 3, h = bh & 7;
  const int q0 = blockIdx.x * 128;

  __shared__ __bf16 ksh[64][72];      // K hi tile [key][kd]
  __shared__ __bf16 ksl[64][72];      // K lo tile
  __shared__ __bf16 vts[64][72];      // V^T tile [vd][key]
  __shared__ __bf16 pst[4][2][16][72];// P [wave][qm][qrow][key]

  const size_t base = (size_t)bh * SS * KDIM;
  const int srow = t >> 2, sc0 = (t & 3) * 16;

  // Q fragments direct from global (read once)
  bf16x8 aqh[2][2], aql[2][2];
#pragma unroll
  for (int qm = 0; qm < 2; ++qm) {
    int qrow = q0 + w * 32 + qm * 16 + (l & 15);
#pragma unroll
    for (int kb = 0; kb < 2; ++kb) {
      size_t off = base + (size_t)qrow * KDIM + kb * 32 + (l >> 4) * 8;
      aqh[qm][kb] = *(const bf16x8*)&qhg[off];
      aql[qm][kb] = *(const bf16x8*)&qlg[off];
    }
  }

  const float sc_h = scales[h];
  float m_s[2], lsum_s[2];
  f32x4 oacc[2][4];
#pragma unroll
  for (int qm = 0; qm < 2; ++qm) {
    m_s[qm] = -1e30f; lsum_s[qm] = 0.f;
#pragma unroll
    for (int nb = 0; nb < 4; ++nb) oacc[qm][nb] = f32x4{0.f, 0.f, 0.f, 0.f};
  }

  for (int kt = 0; kt < SS / 64; ++kt) {
    __syncthreads();
    {
      size_t off = base + (size_t)(kt * 64 + srow) * KDIM + sc0;
      const uint4* skh = (const uint4*)(khg + off);
      uint4* dkh = (uint4*)&ksh[srow][sc0];
      dkh[0] = skh[0]; dkh[1] = skh[1];
      const uint4* skl = (const uint4*)(klg + off);
      uint4* dkl = (uint4*)&ksl[srow][sc0];
      dkl[0] = skl[0]; dkl[1] = skl[1];
      // V^T: row = vd, cols = keys
      const uint4* sv = (const uint4*)(vTg + (size_t)bh * KDIM * SS + (size_t)srow * SS + kt * 64 + sc0);
      uint4* dv = (uint4*)&vts[srow][sc0];
      dv[0] = sv[0]; dv[1] = sv[1];
    }
    __syncthreads();

#pragma unroll
    for (int qm = 0; qm < 2; ++qm) {
      // St tiles: lane holds keys jb*16+(l>>4)*4+r for q-row (l&15)
      f32x4 st[4];
#pragma unroll
      for (int jb = 0; jb < 4; ++jb) {
        st[jb] = f32x4{0.f, 0.f, 0.f, 0.f};
#pragma unroll
        for (int kb = 0; kb < 2; ++kb) {
          bf16x8 bkh = *(const bf16x8*)&ksh[jb * 16 + (l & 15)][kb * 32 + (l >> 4) * 8];
          bf16x8 bkl = *(const bf16x8*)&ksl[jb * 16 + (l & 15)][kb * 32 + (l >> 4) * 8];
          st[jb] = __builtin_amdgcn_mfma_f32_16x16x32_bf16(bkh, aqh[qm][kb], st[jb], 0, 0, 0);
          st[jb] = __builtin_amdgcn_mfma_f32_16x16x32_bf16(bkh, aql[qm][kb], st[jb], 0, 0, 0);
          st[jb] = __builtin_amdgcn_mfma_f32_16x16x32_bf16(bkl, aqh[qm][kb], st[jb], 0, 0, 0);
        }
      }

      // softmax over this tile's 64 keys (16 per lane, 4 lane-groups share row)
      float mt = -1e30f;
#pragma unroll
      for (int jb = 0; jb < 4; ++jb)
#pragma unroll
        for (int r = 0; r < 4; ++r) { st[jb][r] *= sc_h; mt = fmaxf(mt, st[jb][r]); }
      mt = fmaxf(mt, __shfl_xor(mt, 16, 64));
      mt = fmaxf(mt, __shfl_xor(mt, 32, 64));
      float mn = fmaxf(m_s[qm], mt);
      float resc = __expf(m_s[qm] - mn);
      m_s[qm] = mn;
      float psum = 0.f;
      __bf16 pb4[4][4] __attribute__((aligned(8)));
#pragma unroll
      for (int jb = 0; jb < 4; ++jb)
#pragma unroll
        for (int r = 0; r < 4; ++r) {
          float p = __expf(st[jb][r] - mn);
          psum += p;
          pb4[jb][r] = (__bf16)p;
        }
      psum += __shfl_xor(psum, 16, 64);
      psum += __shfl_xor(psum, 32, 64);
      lsum_s[qm] = lsum_s[qm] * resc + psum;
#pragma unroll
      for (int jb = 0; jb < 4; ++jb)
        *(uint2*)&pst[w][qm][l & 15][jb * 16 + (l >> 4) * 4] = *(uint2*)pb4[jb];

      // rescale O rows (rows (l>>4)*4+j; resc held by lane (row&15))
#pragma unroll
      for (int j = 0; j < 4; ++j) {
        float rj = __shfl(resc, (l >> 4) * 4 + j, 64);
#pragma unroll
        for (int nb = 0; nb < 4; ++nb) oacc[qm][nb][j] *= rj;
      }

      // O += P V  (A = P from LDS, B = V^T fragments)
#pragma unroll
      for (int kb = 0; kb < 2; ++kb) {
        bf16x8 pa = *(const bf16x8*)&pst[w][qm][l & 15][kb * 32 + (l >> 4) * 8];
#pragma unroll
        for (int nb = 0; nb < 4; ++nb) {
          bf16x8 bv = *(const bf16x8*)&vts[nb * 16 + (l & 15)][kb * 32 + (l >> 4) * 8];
          oacc[qm][nb] = __builtin_amdgcn_mfma_f32_16x16x32_bf16(pa, bv, oacc[qm][nb], 0, 0, 0);
        }
      }
    }
  }

  // epilogue: ctx[row, h*64+vd] = mask_i * O / lsum
#pragma unroll
  for (int qm = 0; qm < 2; ++qm) {
#pragma unroll
    for (int j = 0; j < 4; ++j) {
      int rl_ = (l >> 4) * 4 + j;
      float lr = __shfl(lsum_s[qm], rl_, 64);
      int row = q0 + w * 32 + qm * 16 + rl_;          // = b*SS + s
      float mi = mask[(size_t)b * SS + (row & 2047)];
      float inv = mi / lr;
#pragma unroll
      for (int nb = 0; nb < 4; ++nb) {
        int vd = nb * 16 + (l & 15);
        ctx[((size_t)b * SS + row) * (HH * KDIM) + h * KDIM + vd] = oacc[qm][nb][j] * inv;
      }
    }
  }
}

// ---------------- Kernel C: output projection (fp32) -------------------------
__global__ __launch_bounds__(256) void oproj_kernel(
    const float* __restrict__ ctx, const float* __restrict__ Wo,
    float* __restrict__ out) {
  __shared__ float xs[16 * 512];
  const int t = threadIdx.x;
  const size_t rowbase = (size_t)blockIdx.x * 16;
  for (int i = t; i < 16 * 512; i += 256) xs[i] = ctx[rowbase * 512 + i];
  __syncthreads();

  const int col = t & 63, rg = t >> 6;
  float acc[4] = {0.f, 0.f, 0.f, 0.f};
  for (int d4 = 0; d4 < 128; ++d4) {
    float wv[4];
#pragma unroll
    for (int u = 0; u < 4; ++u) wv[u] = Wo[(size_t)(d4 * 4 + u) * 64 + col];
#pragma unroll
    for (int rr = 0; rr < 4; ++rr) {
      float4 xv = *(const float4*)&xs[(rg * 4 + rr) * 512 + d4 * 4];
      acc[rr] += xv.x * wv[0];
      acc[rr] += xv.y * wv[1];
      acc[rr] += xv.z * wv[2];
      acc[rr] += xv.w * wv[3];
    }
  }
#pragma unroll
  for (int rr = 0; rr < 4; ++rr)
    out[(rowbase + rg * 4 + rr) * 64 + col] = acc[rr];
}

// ---------------- launch -----------------------------------------------------
extern "C" void kernel_launch(void* const* d_in, const int* in_sizes, int n_in,
                              void* d_out, int out_size, void* d_ws, size_t ws_size,
                              hipStream_t stream) {
  const float* x     = (const float*)d_in[0];
  const float* mask  = (const float*)d_in[1];
  const float* Wq    = (const float*)d_in[2];
  const float* Wk    = (const float*)d_in[3];
  const float* Wv    = (const float*)d_in[4];
  const float* Wo    = (const float*)d_in[5];
  const float* scales= (const float*)d_in[6];
  float* out = (float*)d_out;

  char* ws = (char*)d_ws;
  const size_t xb = (size_t)BB * SS * DD * sizeof(__bf16);         // 8MB
  const size_t wb = (size_t)3 * 512 * DD * sizeof(__bf16);         // 1.5MB
  const size_t qb = (size_t)BB * HH * SS * KDIM * sizeof(__bf16);  // 8MB

  __bf16* xhb = (__bf16*)(ws);
  __bf16* xlb = (__bf16*)(ws + xb);
  __bf16* wthb = (__bf16*)(ws + 2 * xb);
  __bf16* wtlb = (__bf16*)(ws + 2 * xb + wb);
  char* p = ws + 2 * xb + 2 * wb;
  __bf16* qhb = (__bf16*)(p);
  __bf16* qlb = (__bf16*)(p + qb);
  __bf16* khb = (__bf16*)(p + 2 * qb);
  __bf16* klb = (__bf16*)(p + 3 * qb);
  __bf16* vTb = (__bf16*)(p + 4 * qb);
  float*  ctx = (float*)(p + 5 * qb);

  convert_x<<<2048, 256, 0, stream>>>(x, xhb, xlb);
  convert_w<<<dim3(8, 24), 256, 0, stream>>>(Wq, Wk, Wv, wthb, wtlb);
  qkv_gemm<<<dim3(12, 64), 256, 0, stream>>>(xhb, xlb, wthb, wtlb, mask,
                                             qhb, qlb, khb, klb, vTb);
  attn_kernel<<<dim3(SS / 128, BB * HH), 256, 0, stream>>>(qhb, qlb, khb, klb, vTb, mask, scales, ctx);
  oproj_kernel<<<512, 256, 0, stream>>>(ctx, Wo, out);
}

// Round 6
// 181.705 us; speedup vs baseline: 2.1862x; 1.1911x over previous
//
#include <hip/hip_runtime.h>
#include <hip/hip_bf16.h>

// Problem: B=4, S=2048, D=512, H=8, KD=VD=64.
// out[b,s,:] = concat_h( softmax(qk^T*scale_h) @ (v*mask_j) * mask_i ) @ Wo
// Softmax denominator is UNMASKED (mask applied post-softmax, per reference).
// Precision: GEMM inputs bf16 hi+lo split; products = hi*hi + hi*lo + lo*hi.
// Attention v3: 32x32x16 MFMA, swapped QK^T AND swapped PV (O^T), XOR-swizzled
// LDS, exp2-domain softmax (scale*log2e folded into Q), defer-max rescale.

typedef __bf16 bf16x8 __attribute__((ext_vector_type(8)));
typedef float  f32x4  __attribute__((ext_vector_type(4)));
typedef float  f32x16 __attribute__((ext_vector_type(16)));

#define BB 4
#define SS 2048
#define DD 512
#define HH 8
#define KDIM 64

#define EXP2F(x) __builtin_amdgcn_exp2f(x)

#define GLOAD_LDS16(gp, lp)                                                   \
  __builtin_amdgcn_global_load_lds(                                          \
      (const __attribute__((address_space(1))) void*)(gp),                    \
      (__attribute__((address_space(3))) void*)(lp), 16, 0, 0)

// swizzled byte offset within a [rows][64] bf16 tile (128B rows)
#define SWZ(row, bc) ((row) * 128 + ((bc) ^ (((row) & 7) << 4)))

// ---------------- convert_x: x fp32 -> xh, xl bf16 [8192,512] ----------------
__global__ __launch_bounds__(256) void convert_x(
    const float* __restrict__ x, __bf16* __restrict__ xh, __bf16* __restrict__ xl) {
  size_t i = ((size_t)blockIdx.x * 256 + threadIdx.x) * 8;
  float4 a = *(const float4*)&x[i];
  float4 b = *(const float4*)&x[i + 4];
  float vv[8] = {a.x, a.y, a.z, a.w, b.x, b.y, b.z, b.w};
  __bf16 hb[8], lb[8];
#pragma unroll
  for (int u = 0; u < 8; ++u) {
    hb[u] = (__bf16)vv[u];
    lb[u] = (__bf16)(vv[u] - (float)hb[u]);
  }
  *(uint4*)&xh[i] = *(uint4*)hb;
  *(uint4*)&xl[i] = *(uint4*)lb;
}

// ---------------- convert_w: Wq/Wk/Wv [8,512,64] -> wt hi/lo [1536][512] -----
__global__ __launch_bounds__(256) void convert_w(
    const float* __restrict__ Wq, const float* __restrict__ Wk,
    const float* __restrict__ Wv, __bf16* __restrict__ wth,
    __bf16* __restrict__ wtl) {
  __shared__ float s_tile[64][65];
  const int t = threadIdx.x;
  const int kb = blockIdx.x;          // 0..7
  const int hw = blockIdx.y;          // 0..23
  const int which = hw >> 3, h = hw & 7;
  const float* W = (which == 0) ? Wq : (which == 1) ? Wk : Wv;
  const float* src = W + (size_t)h * DD * KDIM + (size_t)kb * 64 * KDIM;

  {
    int kk = t >> 2, c0 = (t & 3) * 16;
#pragma unroll
    for (int u = 0; u < 4; ++u)
      *(float4*)&s_tile[kk][c0 + u * 4] = *(const float4*)&src[kk * KDIM + c0 + u * 4];
  }
  __syncthreads();

  int kd = t >> 2, kk0 = (t & 3) * 16;
  int n = which * 512 + h * 64 + kd;
  __bf16 hb[16], lb[16];
#pragma unroll
  for (int u = 0; u < 16; ++u) {
    float val = s_tile[kk0 + u][kd];
    hb[u] = (__bf16)val;
    lb[u] = (__bf16)(val - (float)hb[u]);
  }
  size_t off = (size_t)n * DD + kb * 64 + kk0;
  *(uint4*)&wth[off] = *(uint4*)&hb[0];
  *(uint4*)&wth[off + 8] = *(uint4*)&hb[8];
  *(uint4*)&wtl[off] = *(uint4*)&lb[0];
  *(uint4*)&wtl[off + 8] = *(uint4*)&lb[8];
}

// ---------------- qkv_gemm: [8192,512] @ [512,1536] via bf16 hi/lo MFMA ------
// Epilogue: q scaled by scales[h]*log2e, q/k hi+lo bf16 [B*H,S,64];
// v -> premasked V^T [B*H,64,S].
__global__ __launch_bounds__(256) void qkv_gemm(
    const __bf16* __restrict__ xh, const __bf16* __restrict__ xl,
    const __bf16* __restrict__ wth, const __bf16* __restrict__ wtl,
    const float* __restrict__ mask, const float* __restrict__ scales,
    __bf16* __restrict__ qh, __bf16* __restrict__ ql,
    __bf16* __restrict__ kh, __bf16* __restrict__ kl,
    __bf16* __restrict__ vT) {
  __shared__ __bf16 Ah[128 * 32], Al[128 * 32], Bh[128 * 32], Bl[128 * 32];
  const int t = threadIdx.x, l = t & 63, w = t >> 6;
  const int wr = w >> 1, wc = w & 1;
  const int m0 = blockIdx.y * 128, n0 = blockIdx.x * 128;

  f32x4 acc[4][4];
#pragma unroll
  for (int m = 0; m < 4; ++m)
#pragma unroll
    for (int n = 0; n < 4; ++n) acc[m][n] = f32x4{0.f, 0.f, 0.f, 0.f};

  const int rl = l >> 2, ce = (l & 3) * 8;

  for (int kt = 0; kt < 16; ++kt) {
    const int k0 = kt * 32;
    __syncthreads();
#pragma unroll
    for (int i = 0; i < 2; ++i) {
      const int row = w * 32 + i * 16;
      const size_t aoff = (size_t)(m0 + row + rl) * DD + k0 + ce;
      const size_t boff = (size_t)(n0 + row + rl) * DD + k0 + ce;
      GLOAD_LDS16(xh + aoff, &Ah[row * 32]);
      GLOAD_LDS16(xl + aoff, &Al[row * 32]);
      GLOAD_LDS16(wth + boff, &Bh[row * 32]);
      GLOAD_LDS16(wtl + boff, &Bl[row * 32]);
    }
    __syncthreads();

    bf16x8 ah[4], al[4], bh[4], bl[4];
#pragma unroll
    for (int m = 0; m < 4; ++m) {
      int r = wr * 64 + m * 16 + (l & 15);
      ah[m] = *(const bf16x8*)&Ah[r * 32 + (l >> 4) * 8];
      al[m] = *(const bf16x8*)&Al[r * 32 + (l >> 4) * 8];
    }
#pragma unroll
    for (int n = 0; n < 4; ++n) {
      int r = wc * 64 + n * 16 + (l & 15);
      bh[n] = *(const bf16x8*)&Bh[r * 32 + (l >> 4) * 8];
      bl[n] = *(const bf16x8*)&Bl[r * 32 + (l >> 4) * 8];
    }
#pragma unroll
    for (int m = 0; m < 4; ++m)
#pragma unroll
      for (int n = 0; n < 4; ++n) {
        acc[m][n] = __builtin_amdgcn_mfma_f32_16x16x32_bf16(ah[m], bh[n], acc[m][n], 0, 0, 0);
        acc[m][n] = __builtin_amdgcn_mfma_f32_16x16x32_bf16(ah[m], bl[n], acc[m][n], 0, 0, 0);
        acc[m][n] = __builtin_amdgcn_mfma_f32_16x16x32_bf16(al[m], bh[n], acc[m][n], 0, 0, 0);
      }
  }

#pragma unroll
  for (int n = 0; n < 4; ++n) {
    int colg = n0 + wc * 64 + n * 16 + (l & 15);
    int which = colg >> 9, rem = colg & 511;
    int h = rem >> 6, kd = rem & 63;
    float qsc = (which == 0) ? scales[h] * 1.44269504f : 1.f;
#pragma unroll
    for (int m = 0; m < 4; ++m) {
      int row0 = m0 + wr * 64 + m * 16 + (l >> 4) * 4;  // 4 consecutive rows
      if (which == 2) {
        int b = row0 >> 11, s0 = row0 & 2047;
        __bf16 tmp[4] __attribute__((aligned(8)));
#pragma unroll
        for (int j = 0; j < 4; ++j)
          tmp[j] = (__bf16)(acc[m][n][j] * mask[row0 + j]);
        *(uint2*)&vT[((size_t)(b * HH + h) * KDIM + kd) * SS + s0] = *(uint2*)tmp;
      } else {
        __bf16* dh = (which == 0) ? qh : kh;
        __bf16* dl = (which == 0) ? ql : kl;
#pragma unroll
        for (int j = 0; j < 4; ++j) {
          int row = row0 + j;
          int b = row >> 11, s = row & 2047;
          size_t idx = (((size_t)b * HH + h) * SS + s) * KDIM + kd;
          float val = acc[m][n][j] * qsc;
          __bf16 hi = (__bf16)val;
          dh[idx] = hi;
          dl[idx] = (__bf16)(val - (float)hi);
        }
      }
    }
  }
}

// ---------------- Kernel B: flash attention v3 (32x32 MFMA) ------------------
// grid (S/128, B*H) x 256 thr (4 waves). Wave w owns q rows [w*32, w*32+32).
// Lane owns q-row (l&31). QK^T: St = mfma(K, Q); PV: O^T = mfma(V, P).
__global__ __launch_bounds__(256) void attn_kernel(
    const __bf16* __restrict__ qhg, const __bf16* __restrict__ qlg,
    const __bf16* __restrict__ khg, const __bf16* __restrict__ klg,
    const __bf16* __restrict__ vTg, const float* __restrict__ mask,
    float* __restrict__ ctx) {
  const int t = threadIdx.x;
  const int l = t & 63, w = t >> 6;
  const int lr = l & 31, hi = l >> 5;
  const int bh = blockIdx.y, b = bh >> 3, h = bh & 7;
  const int q0 = blockIdx.x * 128;

  __shared__ __bf16 ksh[64 * 64];   // K hi tile, swizzled
  __shared__ __bf16 ksl[64 * 64];   // K lo tile, swizzled
  __shared__ __bf16 vts[64 * 64];   // V^T tile, swizzled
  __shared__ __bf16 ps[4][32 * 64]; // per-wave P, swizzled

  const size_t base = (size_t)bh * SS * KDIM;
  const size_t vbase = (size_t)bh * KDIM * SS;

  // Q fragments from global (B-operand: col=q-row=lr, k = hi*8+j)
  bf16x8 qfh[4], qfl[4];
  const int s_q = q0 + w * 32 + lr;
#pragma unroll
  for (int kb = 0; kb < 4; ++kb) {
    size_t off = base + (size_t)s_q * KDIM + kb * 16 + hi * 8;
    qfh[kb] = *(const bf16x8*)&qhg[off];
    qfl[kb] = *(const bf16x8*)&qlg[off];
  }

  float m_s = -1e30f, lsum = 0.f;
  f32x16 oacc[2] = {};

  for (int kt = 0; kt < SS / 64; ++kt) {
    __syncthreads();
    // stage K hi/lo + V^T, 8 rows per call, pre-swizzled global source
#pragma unroll
    for (int c = 0; c < 2; ++c) {
      const int r = w * 16 + c * 8 + (l >> 3);
      const int ecol = ((l & 7) * 8) ^ (((l >> 3) & 7) * 8);
      size_t koff = base + (size_t)(kt * 64 + r) * KDIM + ecol;
      size_t voff = vbase + (size_t)r * SS + kt * 64 + ecol;
      GLOAD_LDS16(khg + koff, ksh + (w * 16 + c * 8) * 64);
      GLOAD_LDS16(klg + koff, ksl + (w * 16 + c * 8) * 64);
      GLOAD_LDS16(vTg + voff, vts + (w * 16 + c * 8) * 64);
    }
    __syncthreads();

    // QK^T: St[key][qrow], A = K rows (jb*32+lr), B = Q
    f32x16 st2[2];
#pragma unroll
    for (int jb = 0; jb < 2; ++jb) {
      f32x16 acc = {};
      const int krow = jb * 32 + lr;
#pragma unroll
      for (int kb = 0; kb < 4; ++kb) {
        bf16x8 kfh = *(const bf16x8*)((const char*)ksh + SWZ(krow, kb * 32 + hi * 16));
        bf16x8 kfl = *(const bf16x8*)((const char*)ksl + SWZ(krow, kb * 32 + hi * 16));
        acc = __builtin_amdgcn_mfma_f32_32x32x16_bf16(kfh, qfh[kb], acc, 0, 0, 0);
        acc = __builtin_amdgcn_mfma_f32_32x32x16_bf16(kfh, qfl[kb], acc, 0, 0, 0);
        acc = __builtin_amdgcn_mfma_f32_32x32x16_bf16(kfl, qfh[kb], acc, 0, 0, 0);
      }
      st2[jb] = acc;
    }

    // tile max (scores already in exp2 domain via Q pre-scale)
    float mt = -1e30f;
#pragma unroll
    for (int jb = 0; jb < 2; ++jb)
#pragma unroll
      for (int rr = 0; rr < 16; ++rr) mt = fmaxf(mt, st2[jb][rr]);
    mt = fmaxf(mt, __shfl_xor(mt, 32, 64));

    // defer-max: rescale only if some lane grew past threshold
    if (!__all(mt <= m_s + 11.5f)) {
      float mn = fmaxf(m_s, mt);
      float rs = EXP2F(m_s - mn);
      m_s = mn;
      lsum *= rs;
#pragma unroll
      for (int nb = 0; nb < 2; ++nb)
#pragma unroll
        for (int rr = 0; rr < 16; ++rr) oacc[nb][rr] *= rs;
    }

    // P = exp2(St - m), write to per-wave LDS (row = qrow = lr)
    float psum = 0.f;
#pragma unroll
    for (int jb = 0; jb < 2; ++jb)
#pragma unroll
      for (int g = 0; g < 4; ++g) {
        __bf16 tmp[4] __attribute__((aligned(8)));
#pragma unroll
        for (int r = 0; r < 4; ++r) {
          float p = EXP2F(st2[jb][g * 4 + r] - m_s);
          psum += p;
          tmp[r] = (__bf16)p;
        }
        *(uint2*)((char*)&ps[w][0] + SWZ(lr, jb * 64 + g * 16 + hi * 8)) = *(uint2*)tmp;
      }
    psum += __shfl_xor(psum, 32, 64);
    lsum += psum;

    // O^T += V P: A = V^T rows (vd), B = P cols (qrow=lr)
#pragma unroll
    for (int kb = 0; kb < 4; ++kb) {
      bf16x8 pf = *(const bf16x8*)((const char*)&ps[w][0] + SWZ(lr, kb * 32 + hi * 16));
#pragma unroll
      for (int nb = 0; nb < 2; ++nb) {
        bf16x8 vf = *(const bf16x8*)((const char*)vts + SWZ(nb * 32 + lr, kb * 32 + hi * 16));
        oacc[nb] = __builtin_amdgcn_mfma_f32_32x32x16_bf16(vf, pf, oacc[nb], 0, 0, 0);
      }
    }
  }

  // epilogue: lane owns q-row s_q; D rows = vd = (rr&3)+8*(rr>>2)+4*hi+nb*32
  const float inv = mask[b * SS + s_q] / lsum;
  float* dst = &ctx[((size_t)b * SS + s_q) * (HH * KDIM) + h * KDIM];
#pragma unroll
  for (int nb = 0; nb < 2; ++nb)
#pragma unroll
    for (int g = 0; g < 4; ++g) {
      float4 o;
      o.x = oacc[nb][g * 4 + 0] * inv;
      o.y = oacc[nb][g * 4 + 1] * inv;
      o.z = oacc[nb][g * 4 + 2] * inv;
      o.w = oacc[nb][g * 4 + 3] * inv;
      *(float4*)&dst[nb * 32 + g * 8 + hi * 4] = o;
    }
}

// ---------------- Kernel C: output projection (fp32) -------------------------
__global__ __launch_bounds__(256) void oproj_kernel(
    const float* __restrict__ ctx, const float* __restrict__ Wo,
    float* __restrict__ out) {
  __shared__ float xs[16 * 512];
  const int t = threadIdx.x;
  const size_t rowbase = (size_t)blockIdx.x * 16;
  for (int i = t; i < 16 * 512; i += 256) xs[i] = ctx[rowbase * 512 + i];
  __syncthreads();

  const int col = t & 63, rg = t >> 6;
  float acc[4] = {0.f, 0.f, 0.f, 0.f};
  for (int d4 = 0; d4 < 128; ++d4) {
    float wv[4];
#pragma unroll
    for (int u = 0; u < 4; ++u) wv[u] = Wo[(size_t)(d4 * 4 + u) * 64 + col];
#pragma unroll
    for (int rr = 0; rr < 4; ++rr) {
      float4 xv = *(const float4*)&xs[(rg * 4 + rr) * 512 + d4 * 4];
      acc[rr] += xv.x * wv[0];
      acc[rr] += xv.y * wv[1];
      acc[rr] += xv.z * wv[2];
      acc[rr] += xv.w * wv[3];
    }
  }
#pragma unroll
  for (int rr = 0; rr < 4; ++rr)
    out[(rowbase + rg * 4 + rr) * 64 + col] = acc[rr];
}

// ---------------- launch -----------------------------------------------------
extern "C" void kernel_launch(void* const* d_in, const int* in_sizes, int n_in,
                              void* d_out, int out_size, void* d_ws, size_t ws_size,
                              hipStream_t stream) {
  const float* x     = (const float*)d_in[0];
  const float* mask  = (const float*)d_in[1];
  const float* Wq    = (const float*)d_in[2];
  const float* Wk    = (const float*)d_in[3];
  const float* Wv    = (const float*)d_in[4];
  const float* Wo    = (const float*)d_in[5];
  const float* scales= (const float*)d_in[6];
  float* out = (float*)d_out;

  char* ws = (char*)d_ws;
  const size_t xb = (size_t)BB * SS * DD * sizeof(__bf16);         // 8MB
  const size_t wb = (size_t)3 * 512 * DD * sizeof(__bf16);         // 1.5MB
  const size_t qb = (size_t)BB * HH * SS * KDIM * sizeof(__bf16);  // 8MB

  __bf16* xhb = (__bf16*)(ws);
  __bf16* xlb = (__bf16*)(ws + xb);
  __bf16* wthb = (__bf16*)(ws + 2 * xb);
  __bf16* wtlb = (__bf16*)(ws + 2 * xb + wb);
  char* p = ws + 2 * xb + 2 * wb;
  __bf16* qhb = (__bf16*)(p);
  __bf16* qlb = (__bf16*)(p + qb);
  __bf16* khb = (__bf16*)(p + 2 * qb);
  __bf16* klb = (__bf16*)(p + 3 * qb);
  __bf16* vTb = (__bf16*)(p + 4 * qb);
  float*  ctx = (float*)(p + 5 * qb);

  convert_x<<<2048, 256, 0, stream>>>(x, xhb, xlb);
  convert_w<<<dim3(8, 24), 256, 0, stream>>>(Wq, Wk, Wv, wthb, wtlb);
  qkv_gemm<<<dim3(12, 64), 256, 0, stream>>>(xhb, xlb, wthb, wtlb, mask, scales,
                                             qhb, qlb, khb, klb, vTb);
  attn_kernel<<<dim3(SS / 128, BB * HH), 256, 0, stream>>>(qhb, qlb, khb, klb, vTb, mask, ctx);
  oproj_kernel<<<512, 256, 0, stream>>>(ctx, Wo, out);
}

// Round 8
// 115.171 us; speedup vs baseline: 3.4491x; 1.5777x over previous
//
#include <hip/hip_runtime.h>
#include <hip/hip_bf16.h>

// Problem: B=4, S=2048, D=512, H=8, KD=VD=64.
// out[b,s,:] = concat_h( softmax(qk^T*scale_h) @ (v*mask_j) * mask_i ) @ Wo
// Softmax denominator is UNMASKED (mask applied post-softmax, per reference).
// v4: fp16 (2^-11) everywhere instead of bf16 hi/lo. QK^T 1 MFMA, P held in
// registers (cvt_pkrtz + shfl_xor(32) half-exchange), oproj via MFMA.

typedef _Float16 f16x8 __attribute__((ext_vector_type(8)));
typedef float    f32x4  __attribute__((ext_vector_type(4)));
typedef float    f32x16 __attribute__((ext_vector_type(16)));

#define BB 4
#define SS 2048
#define DD 512
#define HH 8
#define KDIM 64

#define EXP2F(x) __builtin_amdgcn_exp2f(x)

#define GLOAD_LDS16(gp, lp)                                                   \
  __builtin_amdgcn_global_load_lds(                                          \
      (const __attribute__((address_space(1))) void*)(gp),                    \
      (__attribute__((address_space(3))) void*)(lp), 16, 0, 0)

// swizzled byte offset within a [rows][64] fp16 tile (128B rows)
#define SWZ(row, bc) ((row) * 128 + ((bc) ^ (((row) & 7) << 4)))

static __device__ __forceinline__ unsigned pk2(float a, float b) {
  auto h = __builtin_amdgcn_cvt_pkrtz(a, b);  // __fp16 ext_vector(2)
  return __builtin_bit_cast(unsigned, h);
}

union PU { unsigned u[4]; f16x8 v; };

// ---------------- convert_x: x fp32 -> xf fp16 [8192,512] --------------------
__global__ __launch_bounds__(256) void convert_x(
    const float* __restrict__ x, _Float16* __restrict__ xf) {
  size_t i = ((size_t)blockIdx.x * 256 + threadIdx.x) * 8;
  float4 a = *(const float4*)&x[i];
  float4 b = *(const float4*)&x[i + 4];
  float vv[8] = {a.x, a.y, a.z, a.w, b.x, b.y, b.z, b.w};
  _Float16 hb[8];
#pragma unroll
  for (int u = 0; u < 8; ++u) hb[u] = (_Float16)vv[u];
  *(uint4*)&xf[i] = *(uint4*)hb;
}

// ---------------- convert_w: Wq/Wk/Wv [8,512,64] -> wtf fp16 [1536][512] -----
__global__ __launch_bounds__(256) void convert_w(
    const float* __restrict__ Wq, const float* __restrict__ Wk,
    const float* __restrict__ Wv, _Float16* __restrict__ wtf) {
  __shared__ float s_tile[64][65];
  const int t = threadIdx.x;
  const int kb = blockIdx.x;          // 0..7
  const int hw = blockIdx.y;          // 0..23
  const int which = hw >> 3, h = hw & 7;
  const float* W = (which == 0) ? Wq : (which == 1) ? Wk : Wv;
  const float* src = W + (size_t)h * DD * KDIM + (size_t)kb * 64 * KDIM;

  {
    int kk = t >> 2, c0 = (t & 3) * 16;
#pragma unroll
    for (int u = 0; u < 4; ++u)
      *(float4*)&s_tile[kk][c0 + u * 4] = *(const float4*)&src[kk * KDIM + c0 + u * 4];
  }
  __syncthreads();

  int kd = t >> 2, kk0 = (t & 3) * 16;
  int n = which * 512 + h * 64 + kd;
  _Float16 hb[16];
#pragma unroll
  for (int u = 0; u < 16; ++u) hb[u] = (_Float16)s_tile[kk0 + u][kd];
  size_t off = (size_t)n * DD + kb * 64 + kk0;
  *(uint4*)&wtf[off] = *(uint4*)&hb[0];
  *(uint4*)&wtf[off + 8] = *(uint4*)&hb[8];
}

// ---------------- convert_wo: Wo [512,64] -> WoT fp16 [64][512] --------------
__global__ __launch_bounds__(256) void convert_wo(
    const float* __restrict__ Wo, _Float16* __restrict__ woT) {
  __shared__ float s_tile[64][65];
  const int t = threadIdx.x;
  const int kb = blockIdx.x;          // 0..7 over K rows
  const float* src = Wo + (size_t)kb * 64 * 64;
  {
    int kk = t >> 2, c0 = (t & 3) * 16;
#pragma unroll
    for (int u = 0; u < 4; ++u)
      *(float4*)&s_tile[kk][c0 + u * 4] = *(const float4*)&src[kk * 64 + c0 + u * 4];
  }
  __syncthreads();
  int col = t >> 2, kk0 = (t & 3) * 16;
  _Float16 hb[16];
#pragma unroll
  for (int u = 0; u < 16; ++u) hb[u] = (_Float16)s_tile[kk0 + u][col];
  size_t off = (size_t)col * DD + kb * 64 + kk0;
  *(uint4*)&woT[off] = *(uint4*)&hb[0];
  *(uint4*)&woT[off + 8] = *(uint4*)&hb[8];
}

// ---------------- qkv_gemm: [8192,512] @ [512,1536] fp16 MFMA ----------------
// Epilogue: q scaled by scales[h]*log2e -> qf; k -> kf; v premasked -> vT.
__global__ __launch_bounds__(256) void qkv_gemm(
    const _Float16* __restrict__ xf, const _Float16* __restrict__ wtf,
    const float* __restrict__ mask, const float* __restrict__ scales,
    _Float16* __restrict__ qf, _Float16* __restrict__ kf,
    _Float16* __restrict__ vT) {
  __shared__ _Float16 Af[128 * 32], Bf[128 * 32];
  const int t = threadIdx.x, l = t & 63, w = t >> 6;
  const int wr = w >> 1, wc = w & 1;
  const int m0 = blockIdx.y * 128, n0 = blockIdx.x * 128;

  f32x4 acc[4][4];
#pragma unroll
  for (int m = 0; m < 4; ++m)
#pragma unroll
    for (int n = 0; n < 4; ++n) acc[m][n] = f32x4{0.f, 0.f, 0.f, 0.f};

  const int rl = l >> 2, ce = (l & 3) * 8;

  for (int kt = 0; kt < 16; ++kt) {
    const int k0 = kt * 32;
    __syncthreads();
#pragma unroll
    for (int i = 0; i < 2; ++i) {
      const int row = w * 32 + i * 16;
      const size_t aoff = (size_t)(m0 + row + rl) * DD + k0 + ce;
      const size_t boff = (size_t)(n0 + row + rl) * DD + k0 + ce;
      GLOAD_LDS16(xf + aoff, &Af[row * 32]);
      GLOAD_LDS16(wtf + boff, &Bf[row * 32]);
    }
    __syncthreads();

    f16x8 ah[4], bh[4];
#pragma unroll
    for (int m = 0; m < 4; ++m) {
      int r = wr * 64 + m * 16 + (l & 15);
      ah[m] = *(const f16x8*)&Af[r * 32 + (l >> 4) * 8];
    }
#pragma unroll
    for (int n = 0; n < 4; ++n) {
      int r = wc * 64 + n * 16 + (l & 15);
      bh[n] = *(const f16x8*)&Bf[r * 32 + (l >> 4) * 8];
    }
#pragma unroll
    for (int m = 0; m < 4; ++m)
#pragma unroll
      for (int n = 0; n < 4; ++n)
        acc[m][n] = __builtin_amdgcn_mfma_f32_16x16x32_f16(ah[m], bh[n], acc[m][n], 0, 0, 0);
  }

#pragma unroll
  for (int n = 0; n < 4; ++n) {
    int colg = n0 + wc * 64 + n * 16 + (l & 15);
    int which = colg >> 9, rem = colg & 511;
    int h = rem >> 6, kd = rem & 63;
    float qsc = (which == 0) ? scales[h] * 1.44269504f : 1.f;
#pragma unroll
    for (int m = 0; m < 4; ++m) {
      int row0 = m0 + wr * 64 + m * 16 + (l >> 4) * 4;  // 4 consecutive rows
      if (which == 2) {
        int b = row0 >> 11, s0 = row0 & 2047;
        _Float16 tmp[4] __attribute__((aligned(8)));
#pragma unroll
        for (int j = 0; j < 4; ++j)
          tmp[j] = (_Float16)(acc[m][n][j] * mask[row0 + j]);
        *(uint2*)&vT[((size_t)(b * HH + h) * KDIM + kd) * SS + s0] = *(uint2*)tmp;
      } else {
        _Float16* dst = (which == 0) ? qf : kf;
#pragma unroll
        for (int j = 0; j < 4; ++j) {
          int row = row0 + j;
          int b = row >> 11, s = row & 2047;
          dst[(((size_t)b * HH + h) * SS + s) * KDIM + kd] =
              (_Float16)(acc[m][n][j] * qsc);
        }
      }
    }
  }
}

// ---------------- Kernel B: flash attention v4 (fp16, reg-P) -----------------
// grid (S/128, B*H) x 256 thr (4 waves). Wave w owns q rows [w*32, w*32+32).
// Lane owns q-row (l&31). QK^T: St = mfma(K, Q); PV: O^T = mfma(V, P).
__global__ __launch_bounds__(256) void attn_kernel(
    const _Float16* __restrict__ qg, const _Float16* __restrict__ kg,
    const _Float16* __restrict__ vTg, const float* __restrict__ mask,
    _Float16* __restrict__ ctxf) {
  const int t = threadIdx.x;
  const int l = t & 63, w = t >> 6;
  const int lr = l & 31, hi = l >> 5;
  const int bh = blockIdx.y, b = bh >> 3, h = bh & 7;
  const int q0 = blockIdx.x * 128;

  __shared__ _Float16 ksf[64 * 64];   // K tile, swizzled (8KB)
  __shared__ _Float16 vts[64 * 64];   // V^T tile, swizzled (8KB)

  const size_t base = (size_t)bh * SS * KDIM;
  const size_t vbase = (size_t)bh * KDIM * SS;

  // Q fragments from global (B-operand: col=q-row=lr, k = hi*8+j)
  f16x8 qfr[4];
  const int s_q = q0 + w * 32 + lr;
#pragma unroll
  for (int kb = 0; kb < 4; ++kb)
    qfr[kb] = *(const f16x8*)&qg[base + (size_t)s_q * KDIM + kb * 16 + hi * 8];

  float m_s = -1e30f, lsum = 0.f;
  f32x16 oacc[2] = {};

  for (int kt = 0; kt < SS / 64; ++kt) {
    __syncthreads();
    // stage K + V^T, 8 rows per gload, pre-swizzled global source
#pragma unroll
    for (int c = 0; c < 2; ++c) {
      const int r = w * 16 + c * 8 + (l >> 3);
      const int ecol = ((l & 7) * 8) ^ (((l >> 3) & 7) * 8);
      size_t koff = base + (size_t)(kt * 64 + r) * KDIM + ecol;
      size_t voff = vbase + (size_t)r * SS + kt * 64 + ecol;
      GLOAD_LDS16(kg + koff, ksf + (w * 16 + c * 8) * 64);
      GLOAD_LDS16(vTg + voff, vts + (w * 16 + c * 8) * 64);
    }
    __syncthreads();

    // QK^T: St[key][qrow], A = K rows (jb*32+lr), B = Q
    f32x16 st2[2];
#pragma unroll
    for (int jb = 0; jb < 2; ++jb) {
      f32x16 acc = {};
      const int krow = jb * 32 + lr;
#pragma unroll
      for (int kb = 0; kb < 4; ++kb) {
        f16x8 kfr = *(const f16x8*)((const char*)ksf + SWZ(krow, kb * 32 + hi * 16));
        acc = __builtin_amdgcn_mfma_f32_32x32x16_f16(kfr, qfr[kb], acc, 0, 0, 0);
      }
      st2[jb] = acc;
    }

    // tile max (scores in exp2 domain via Q pre-scale)
    float mt = -1e30f;
#pragma unroll
    for (int jb = 0; jb < 2; ++jb)
#pragma unroll
      for (int rr = 0; rr < 16; ++rr) mt = fmaxf(mt, st2[jb][rr]);
    mt = fmaxf(mt, __shfl_xor(mt, 32, 64));

    // defer-max: rescale only if some lane grew past threshold
    if (!__all(mt <= m_s + 11.5f)) {
      float mn = fmaxf(m_s, mt);
      float rs = EXP2F(m_s - mn);
      m_s = mn;
      lsum *= rs;
#pragma unroll
      for (int nb = 0; nb < 2; ++nb)
#pragma unroll
        for (int rr = 0; rr < 16; ++rr) oacc[nb][rr] *= rs;
    }

    // P = exp2(St - m) packed to fp16 pairs in registers.
    // wds[jb][g] packs keys {jb*32 + g*8 + 4*hi + 0..3}.
    float psum = 0.f;
    unsigned wds[2][4][2];
#pragma unroll
    for (int jb = 0; jb < 2; ++jb)
#pragma unroll
      for (int g = 0; g < 4; ++g) {
        float p0 = EXP2F(st2[jb][g * 4 + 0] - m_s);
        float p1 = EXP2F(st2[jb][g * 4 + 1] - m_s);
        float p2 = EXP2F(st2[jb][g * 4 + 2] - m_s);
        float p3 = EXP2F(st2[jb][g * 4 + 3] - m_s);
        psum += (p0 + p1) + (p2 + p3);
        wds[jb][g][0] = pk2(p0, p1);
        wds[jb][g][1] = pk2(p2, p3);
      }
    psum += __shfl_xor(psum, 32, 64);
    lsum += psum;

    // O^T += V P: B-frag for MFMA kb needs keys kb*16 + hi*8 + 0..7.
    // own half = wds[jb][gb+hi], partner half via shfl_xor(32) of wds[jb][gb+1-hi].
#pragma unroll
    for (int kb = 0; kb < 4; ++kb) {
      const int jb = kb >> 1, gb = (kb & 1) * 2;
      unsigned ow0 = hi ? wds[jb][gb + 1][0] : wds[jb][gb][0];
      unsigned ow1 = hi ? wds[jb][gb + 1][1] : wds[jb][gb][1];
      unsigned sw0 = hi ? wds[jb][gb][0] : wds[jb][gb + 1][0];
      unsigned sw1 = hi ? wds[jb][gb][1] : wds[jb][gb + 1][1];
      unsigned r0 = (unsigned)__shfl_xor((int)sw0, 32, 64);
      unsigned r1 = (unsigned)__shfl_xor((int)sw1, 32, 64);
      PU pu;
      pu.u[0] = hi ? r0 : ow0;
      pu.u[1] = hi ? r1 : ow1;
      pu.u[2] = hi ? ow0 : r0;
      pu.u[3] = hi ? ow1 : r1;
#pragma unroll
      for (int nb = 0; nb < 2; ++nb) {
        f16x8 vf = *(const f16x8*)((const char*)vts + SWZ(nb * 32 + lr, kb * 32 + hi * 16));
        oacc[nb] = __builtin_amdgcn_mfma_f32_32x32x16_f16(vf, pu.v, oacc[nb], 0, 0, 0);
      }
    }
  }

  // epilogue: lane owns q-row s_q; vd = nb*32 + g*8 + hi*4 + (0..3)
  const float inv = mask[b * SS + s_q] / lsum;
  _Float16* dst = ctxf + ((size_t)b * SS + s_q) * (HH * KDIM) + h * KDIM;
#pragma unroll
  for (int nb = 0; nb < 2; ++nb)
#pragma unroll
    for (int g = 0; g < 4; ++g) {
      uint2 o;
      o.x = pk2(oacc[nb][g * 4 + 0] * inv, oacc[nb][g * 4 + 1] * inv);
      o.y = pk2(oacc[nb][g * 4 + 2] * inv, oacc[nb][g * 4 + 3] * inv);
      *(uint2*)&dst[nb * 32 + g * 8 + hi * 4] = o;
    }
}

// ---------------- oproj: ctx[8192,512] @ Wo[512,64] via fp16 MFMA ------------
// grid 128 blocks x 256 thr. Block: 64 rows. Wave: wr=w>>1 row-half (32 rows),
// wc=w&1 col-half (32 cols).
__global__ __launch_bounds__(256) void oproj_gemm(
    const _Float16* __restrict__ ctxf, const _Float16* __restrict__ woT,
    float* __restrict__ out) {
  __shared__ _Float16 Af[64 * 32], Bf[64 * 32];
  const int t = threadIdx.x, l = t & 63, w = t >> 6;
  const int lr = l & 31, hi = l >> 5;
  const int wr = w >> 1, wc = w & 1;
  const size_t rowbase = (size_t)blockIdx.x * 64;
  const int rl = l >> 2, ce = (l & 3) * 8;

  f32x16 acc = {};
  for (int kt = 0; kt < 16; ++kt) {
    const int k0 = kt * 32;
    __syncthreads();
    {
      const int row = w * 16;
      GLOAD_LDS16(ctxf + (rowbase + row + rl) * DD + k0 + ce, &Af[row * 32]);
      GLOAD_LDS16(woT + (size_t)(row + rl) * DD + k0 + ce, &Bf[row * 32]);
    }
    __syncthreads();
#pragma unroll
    for (int ks = 0; ks < 2; ++ks) {
      f16x8 af = *(const f16x8*)&Af[(wr * 32 + lr) * 32 + ks * 16 + hi * 8];
      f16x8 bf = *(const f16x8*)&Bf[(wc * 32 + lr) * 32 + ks * 16 + hi * 8];
      acc = __builtin_amdgcn_mfma_f32_32x32x16_f16(af, bf, acc, 0, 0, 0);
    }
  }
#pragma unroll
  for (int rr = 0; rr < 16; ++rr) {
    int m = (rr & 3) + 8 * (rr >> 2) + 4 * hi;
    out[(rowbase + wr * 32 + m) * 64 + wc * 32 + lr] = acc[rr];
  }
}

// ---------------- launch -----------------------------------------------------
extern "C" void kernel_launch(void* const* d_in, const int* in_sizes, int n_in,
                              void* d_out, int out_size, void* d_ws, size_t ws_size,
                              hipStream_t stream) {
  const float* x     = (const float*)d_in[0];
  const float* mask  = (const float*)d_in[1];
  const float* Wq    = (const float*)d_in[2];
  const float* Wk    = (const float*)d_in[3];
  const float* Wv    = (const float*)d_in[4];
  const float* Wo    = (const float*)d_in[5];
  const float* scales= (const float*)d_in[6];
  float* out = (float*)d_out;

  char* ws = (char*)d_ws;
  const size_t xb = (size_t)BB * SS * DD * sizeof(_Float16);         // 8MB
  const size_t wb = (size_t)3 * 512 * DD * sizeof(_Float16);         // 1.5MB
  const size_t wob = (size_t)64 * DD * sizeof(_Float16);             // 64KB
  const size_t qb = (size_t)BB * HH * SS * KDIM * sizeof(_Float16);  // 8MB

  _Float16* xfb = (_Float16*)(ws);
  _Float16* wtfb = (_Float16*)(ws + xb);
  _Float16* woTb = (_Float16*)(ws + xb + wb);
  char* p = ws + xb + wb + wob;
  _Float16* qfb = (_Float16*)(p);
  _Float16* kfb = (_Float16*)(p + qb);
  _Float16* vTb = (_Float16*)(p + 2 * qb);
  _Float16* ctxf = (_Float16*)(p + 3 * qb);

  convert_x<<<2048, 256, 0, stream>>>(x, xfb);
  convert_w<<<dim3(8, 24), 256, 0, stream>>>(Wq, Wk, Wv, wtfb);
  convert_wo<<<8, 256, 0, stream>>>(Wo, woTb);
  qkv_gemm<<<dim3(12, 64), 256, 0, stream>>>(xfb, wtfb, mask, scales,
                                             qfb, kfb, vTb);
  attn_kernel<<<dim3(SS / 128, BB * HH), 256, 0, stream>>>(qfb, kfb, vTb, mask, ctxf);
  oproj_gemm<<<128, 256, 0, stream>>>(ctxf, woTb, out);
}